// Round 1
// baseline (928.847 us; speedup 1.0000x reference)
//
#include <hip/hip_runtime.h>
#include <hip/hip_fp16.h>
#include <math.h>

#define S_TOK 8192
#define DMODEL 1024
#define HDIM 4096
#define NEXP 8
#define KTOP2 2
#define CAP 2560
#define SK (S_TOK*KTOP2)
#define NSPLIT 4

typedef _Float16 f16;
typedef _Float16 f16x8 __attribute__((ext_vector_type(8)));
typedef float f32x4 __attribute__((ext_vector_type(4)));

typedef const __attribute__((address_space(1))) void* gas_cp;
typedef __attribute__((address_space(3))) void* las_p;

__device__ __forceinline__ void gload16(const void* g, void* l) {
  __builtin_amdgcn_global_load_lds((gas_cp)g, (las_p)l, 16, 0, 0);
}

// ---------------- ws layout (bytes) ----------------
static const size_t ZERO_OFF  = 0;          // 4096 zeroed every call
static const size_t IMP_OFF   = 4096;       // 8 floats
static const size_t CNT_OFF   = 4160;       // 8 ints (= per-expert load counts)
static const size_t NSEL_OFF  = 4224;       // 8 ints
static const size_t PROBS_OFF = 8192;       // S*8 f32      = 262144
static const size_t TOPKI_OFF = 270336;     // SK i32       = 65536
static const size_t TOPKV_OFF = 335872;     // SK f32       = 65536
static const size_t LISTT_OFF = 401408;     // E*S i32      = 262144
static const size_t LISTW_OFF = 663552;     // E*S f32      = 262144
static const size_t LISTF_OFF = 925696;     // E*S i32      = 262144
static const size_t SELT_OFF  = 1187840;    // E*CAP i32    = 81920
static const size_t SELW_OFF  = 1269760;    // E*CAP f32    = 81920
static const size_t XF16_OFF  = 1351680;    // S*D f16      = 16777216
static const size_t W1T_OFF   = 18128896;   // H*D f16      = 8388608
static const size_t W2T_OFF   = 26517504;   // D*H f16      = 8388608
static const size_t H_OFF     = 34906112;   // CAP*H f16    = 20971520
static const size_t YP_OFF    = 55877632;   // 4*CAP*D f32  = 41943040  (end ~97.8MB)

// ---------------- x -> f16 ----------------
__global__ __launch_bounds__(256) void cvt_x_kernel(const float* __restrict__ x, f16* __restrict__ xf) {
  size_t i = (size_t)blockIdx.x*256 + threadIdx.x;   // 8 elems per thread
  const float4* xv = (const float4*)x;
  float4 a = xv[2*i], b = xv[2*i+1];
  union { f16 h[8]; uint4 u; } p;
  p.h[0]=(f16)a.x; p.h[1]=(f16)a.y; p.h[2]=(f16)a.z; p.h[3]=(f16)a.w;
  p.h[4]=(f16)b.x; p.h[5]=(f16)b.y; p.h[6]=(f16)b.z; p.h[7]=(f16)b.w;
  ((uint4*)xf)[i] = p.u;
}

// ---------------- gate: softmax + top2 ----------------
__global__ __launch_bounds__(256) void gate_kernel(const float* __restrict__ x, const float* __restrict__ Wg,
                                                   float* __restrict__ probs, int* __restrict__ tki,
                                                   float* __restrict__ tkv) {
  int lane = threadIdx.x & 63;
  int t = blockIdx.x*4 + (threadIdx.x >> 6);
  const float* xr = x + (size_t)t*DMODEL;
  float p[NEXP];
  #pragma unroll
  for (int e=0;e<NEXP;e++) p[e] = 0.f;
  for (int d = lane; d < DMODEL; d += 64) {
    float xv = xr[d];
    const float4* wg = (const float4*)(Wg + d*NEXP);
    float4 w0 = wg[0], w1 = wg[1];
    p[0] += xv*w0.x; p[1] += xv*w0.y; p[2] += xv*w0.z; p[3] += xv*w0.w;
    p[4] += xv*w1.x; p[5] += xv*w1.y; p[6] += xv*w1.z; p[7] += xv*w1.w;
  }
  #pragma unroll
  for (int off=32; off; off>>=1) {
    #pragma unroll
    for (int e=0;e<NEXP;e++) p[e] += __shfl_xor(p[e], off);
  }
  float mx = p[0];
  #pragma unroll
  for (int e=1;e<NEXP;e++) mx = fmaxf(mx, p[e]);
  float sum = 0.f;
  #pragma unroll
  for (int e=0;e<NEXP;e++) { p[e] = expf(p[e]-mx); sum += p[e]; }
  float inv = 1.f/sum;
  #pragma unroll
  for (int e=0;e<NEXP;e++) p[e] *= inv;
  if (lane == 0) {
    ((float4*)(probs + t*NEXP))[0] = make_float4(p[0],p[1],p[2],p[3]);
    ((float4*)(probs + t*NEXP))[1] = make_float4(p[4],p[5],p[6],p[7]);
    int i1 = 0; float v1 = p[0];
    #pragma unroll
    for (int e=1;e<NEXP;e++) if (p[e] > v1) { v1 = p[e]; i1 = e; }
    int i2 = -1; float v2 = -1.f;
    #pragma unroll
    for (int e=0;e<NEXP;e++) if (e != i1 && p[e] > v2) { v2 = p[e]; i2 = e; }
    tki[t*2] = i1; tki[t*2+1] = i2;
    tkv[t*2] = v1; tkv[t*2+1] = v2;
  }
}

// ---------------- importance (deterministic column sum) ----------------
__global__ __launch_bounds__(256) void imp_kernel(const float* __restrict__ probs, float* __restrict__ imp) {
  int e = blockIdx.x;
  float s = 0.f;
  for (int t = threadIdx.x; t < S_TOK; t += 256) s += probs[t*NEXP + e];
  #pragma unroll
  for (int off=32; off; off>>=1) s += __shfl_xor(s, off);
  __shared__ float red[4];
  if ((threadIdx.x & 63) == 0) red[threadIdx.x>>6] = s;
  __syncthreads();
  if (threadIdx.x == 0) imp[e] = red[0]+red[1]+red[2]+red[3];
}

// ---------------- compact assignments into per-expert lists ----------------
__global__ __launch_bounds__(256) void compact_kernel(const int* __restrict__ tki, const float* __restrict__ tkv,
                                                      int* __restrict__ cnt, int* __restrict__ listt,
                                                      float* __restrict__ listw, int* __restrict__ listf) {
  int i = blockIdx.x*256 + threadIdx.x;
  int e = tki[i];
  int p = atomicAdd(&cnt[e], 1);
  listt[e*S_TOK + p] = i >> 1;
  listw[e*S_TOK + p] = tkv[i];
  listf[e*S_TOK + p] = i;
}

// ---------------- capacity selection ----------------
__global__ __launch_bounds__(1024) void select_kernel(const int* __restrict__ listt, const float* __restrict__ listw,
                                                      const int* __restrict__ listf, const int* __restrict__ cnt,
                                                      int* __restrict__ selt, float* __restrict__ selw,
                                                      int* __restrict__ nsel) {
  __shared__ float kw[8192];
  __shared__ unsigned short kf[8192];
  int e = blockIdx.x;
  int n = cnt[e];
  const int* lt = listt + e*S_TOK; const float* lw = listw + e*S_TOK; const int* lf = listf + e*S_TOK;
  int* st = selt + e*CAP; float* sw = selw + e*CAP;
  if (threadIdx.x == 0) nsel[e] = (n < CAP) ? n : CAP;
  if (n <= CAP) {
    for (int i = threadIdx.x; i < CAP; i += 1024) {
      if (i < n) { st[i] = lt[i]; sw[i] = lw[i]; }
      else       { st[i] = -1;    sw[i] = 0.f;  }
    }
  } else {
    // exact top-CAP by (score desc, flat_idx asc) — rare path
    for (int i = threadIdx.x; i < n; i += 1024) { kw[i] = lw[i]; kf[i] = (unsigned short)lf[i]; }
    __syncthreads();
    for (int i = threadIdx.x; i < n; i += 1024) {
      float wi = kw[i]; int fi = kf[i];
      int rank = 0;
      for (int j = 0; j < n; ++j) {
        float wj = kw[j];
        rank += (wj > wi) || (wj == wi && (int)kf[j] < fi);
      }
      if (rank < CAP) { st[rank] = lt[i]; sw[rank] = wi; }
    }
  }
}

// ---------------- aux loss ----------------
__global__ void aux_kernel(const float* __restrict__ imp, const int* __restrict__ cnt, float* __restrict__ aux_out) {
  if (threadIdx.x == 0 && blockIdx.x == 0) {
    float a = 0.f;
    #pragma unroll
    for (int e=0;e<NEXP;e++) a += imp[e] * (float)cnt[e];
    *aux_out = a * (8.0f / 67108864.0f);   // * E / (S*S)
  }
}

// ---------------- transpose + fp32->f16:  src[R][C] -> dst[C][R] ----------------
__global__ __launch_bounds__(256) void tcvt_kernel(const float* __restrict__ src, f16* __restrict__ dst,
                                                   int R, int C) {
  __shared__ float tile[32][33];
  int tx = threadIdx.x, ty = threadIdx.y;
  int c0 = blockIdx.x*32, r0 = blockIdx.y*32;
  #pragma unroll
  for (int j=0;j<4;j++)
    tile[ty + 8*j][tx] = src[(size_t)(r0 + ty + 8*j)*C + c0 + tx];
  __syncthreads();
  #pragma unroll
  for (int j=0;j<4;j++)
    dst[(size_t)(c0 + ty + 8*j)*R + r0 + tx] = (f16)tile[tx][ty + 8*j];
}

// ---------------- GEMM1: h = gelu(gather(x) @ W1),  A gathered, B = W1T [H][D] ----------------
__global__ __launch_bounds__(256) void gemm1_kernel(const f16* __restrict__ xf, const f16* __restrict__ w1t,
                                                    const int* __restrict__ selt, const int* __restrict__ nsel_p,
                                                    f16* __restrict__ hbuf, const char* __restrict__ zbuf) {
  int nsel = *nsel_p;
  int m0 = blockIdx.x * 128;
  if (m0 >= nsel) return;
  int n0 = blockIdx.y * 128;

  __shared__ __align__(16) f16 As[2][128*32];
  __shared__ __align__(16) f16 Bs[2][128*32];

  int tid = threadIdx.x;
  int w = tid >> 6, l = tid & 63;

  int rc0 = (w*2+0)*16 + (l>>2);
  int rc1 = (w*2+1)*16 + (l>>2);
  int scol = ((l&3)*16) ^ (((l>>2)&3) << 4);   // swizzled source byte within 64B k-window

  const char *sA0, *sA1;
  {
    int t0 = selt[m0 + rc0];
    int t1 = selt[m0 + rc1];
    sA0 = (t0 >= 0) ? ((const char*)(xf + (size_t)t0*DMODEL) + scol) : (zbuf + scol);
    sA1 = (t1 >= 0) ? ((const char*)(xf + (size_t)t1*DMODEL) + scol) : (zbuf + scol);
  }
  const char* sB0 = (const char*)(w1t + (size_t)(n0+rc0)*DMODEL) + scol;
  const char* sB1 = (const char*)(w1t + (size_t)(n0+rc1)*DMODEL) + scol;

  #define STAGE1(buf, kt) { int ko = (kt)*64; \
      gload16(sA0 + ko, &As[buf][(w*2+0)*512]); \
      gload16(sA1 + ko, &As[buf][(w*2+1)*512]); \
      gload16(sB0 + ko, &Bs[buf][(w*2+0)*512]); \
      gload16(sB1 + ko, &Bs[buf][(w*2+1)*512]); }

  int wr = w >> 1, wc = w & 1;
  int fr = l & 15, kq = l >> 4;
  int rsw = (fr & 3) << 4;
  int aoff[4], boff[4];
  #pragma unroll
  for (int m=0;m<4;m++) aoff[m] = (wr*64 + m*16 + fr)*64 + ((kq*16) ^ rsw);
  #pragma unroll
  for (int n=0;n<4;n++) boff[n] = (wc*64 + n*16 + fr)*64 + ((kq*16) ^ rsw);

  f32x4 zero = {0.f,0.f,0.f,0.f};
  f32x4 acc[4][4];
  #pragma unroll
  for (int m=0;m<4;m++)
    #pragma unroll
    for (int n=0;n<4;n++) acc[m][n] = zero;

  STAGE1(0, 0);
  __syncthreads();
  const int KT = DMODEL/32;
  for (int kt = 0; kt < KT; ++kt) {
    int cur = kt & 1;
    if (kt + 1 < KT) STAGE1(cur^1, kt+1);
    const char* Ab = (const char*)As[cur];
    const char* Bb = (const char*)Bs[cur];
    f16x8 af[4], bf[4];
    #pragma unroll
    for (int m=0;m<4;m++) af[m] = *(const f16x8*)(Ab + aoff[m]);
    #pragma unroll
    for (int n=0;n<4;n++) bf[n] = *(const f16x8*)(Bb + boff[n]);
    #pragma unroll
    for (int m=0;m<4;m++)
      #pragma unroll
      for (int n=0;n<4;n++)
        acc[m][n] = __builtin_amdgcn_mfma_f32_16x16x32_f16(af[m], bf[n], acc[m][n], 0, 0, 0);
    __syncthreads();
  }
  #undef STAGE1

  int rowb = m0 + wr*64;
  int colb = n0 + wc*64;
  #pragma unroll
  for (int m=0;m<4;m++) {
    #pragma unroll
    for (int n=0;n<4;n++) {
      #pragma unroll
      for (int r=0;r<4;r++) {
        int row = rowb + m*16 + kq*4 + r;
        int col = colb + n*16 + fr;
        float v = acc[m][n][r];
        float g = 0.5f * v * (1.0f + erff(v * 0.70710678118654752f));
        hbuf[(size_t)row*HDIM + col] = (f16)g;
      }
    }
  }
}

// ---------------- GEMM2 (split-K): ypart[z] = h @ W2 (K-range z),  B = W2T [D][H] ----------------
__global__ __launch_bounds__(256) void gemm2_kernel(const f16* __restrict__ hbuf, const f16* __restrict__ w2t,
                                                    const int* __restrict__ nsel_p, float* __restrict__ ypart) {
  int nsel = *nsel_p;
  int m0 = blockIdx.x * 128;
  if (m0 >= nsel) return;
  int n0 = blockIdx.y * 128;
  int z  = blockIdx.z;

  __shared__ __align__(16) f16 As[2][128*32];
  __shared__ __align__(16) f16 Bs[2][128*32];

  int tid = threadIdx.x;
  int w = tid >> 6, l = tid & 63;

  int rc0 = (w*2+0)*16 + (l>>2);
  int rc1 = (w*2+1)*16 + (l>>2);
  int scol = ((l&3)*16) ^ (((l>>2)&3) << 4);

  const char* sA0 = (const char*)(hbuf + (size_t)(m0+rc0)*HDIM) + z*2048 + scol;
  const char* sA1 = (const char*)(hbuf + (size_t)(m0+rc1)*HDIM) + z*2048 + scol;
  const char* sB0 = (const char*)(w2t + (size_t)(n0+rc0)*HDIM) + z*2048 + scol;
  const char* sB1 = (const char*)(w2t + (size_t)(n0+rc1)*HDIM) + z*2048 + scol;

  #define STAGE2(buf, kt) { int ko = (kt)*64; \
      gload16(sA0 + ko, &As[buf][(w*2+0)*512]); \
      gload16(sA1 + ko, &As[buf][(w*2+1)*512]); \
      gload16(sB0 + ko, &Bs[buf][(w*2+0)*512]); \
      gload16(sB1 + ko, &Bs[buf][(w*2+1)*512]); }

  int wr = w >> 1, wc = w & 1;
  int fr = l & 15, kq = l >> 4;
  int rsw = (fr & 3) << 4;
  int aoff[4], boff[4];
  #pragma unroll
  for (int m=0;m<4;m++) aoff[m] = (wr*64 + m*16 + fr)*64 + ((kq*16) ^ rsw);
  #pragma unroll
  for (int n=0;n<4;n++) boff[n] = (wc*64 + n*16 + fr)*64 + ((kq*16) ^ rsw);

  f32x4 zero = {0.f,0.f,0.f,0.f};
  f32x4 acc[4][4];
  #pragma unroll
  for (int m=0;m<4;m++)
    #pragma unroll
    for (int n=0;n<4;n++) acc[m][n] = zero;

  STAGE2(0, 0);
  __syncthreads();
  const int KT = 1024/32;   // per split
  for (int kt = 0; kt < KT; ++kt) {
    int cur = kt & 1;
    if (kt + 1 < KT) STAGE2(cur^1, kt+1);
    const char* Ab = (const char*)As[cur];
    const char* Bb = (const char*)Bs[cur];
    f16x8 af[4], bf[4];
    #pragma unroll
    for (int m=0;m<4;m++) af[m] = *(const f16x8*)(Ab + aoff[m]);
    #pragma unroll
    for (int n=0;n<4;n++) bf[n] = *(const f16x8*)(Bb + boff[n]);
    #pragma unroll
    for (int m=0;m<4;m++)
      #pragma unroll
      for (int n=0;n<4;n++)
        acc[m][n] = __builtin_amdgcn_mfma_f32_16x16x32_f16(af[m], bf[n], acc[m][n], 0, 0, 0);
    __syncthreads();
  }
  #undef STAGE2

  int rowb = m0 + wr*64;
  int colb = n0 + wc*64;
  #pragma unroll
  for (int m=0;m<4;m++) {
    #pragma unroll
    for (int n=0;n<4;n++) {
      #pragma unroll
      for (int r=0;r<4;r++) {
        int row = rowb + m*16 + kq*4 + r;
        int col = colb + n*16 + fr;
        ypart[((size_t)z*CAP + row)*DMODEL + col] = acc[m][n][r];
      }
    }
  }
}

// ---------------- combine: out[tok] += w * sum_z ypart[z][slot] ----------------
__global__ __launch_bounds__(256) void combine_kernel(const float* __restrict__ ypart, const int* __restrict__ selt,
                                                      const float* __restrict__ selw, const int* __restrict__ nsel_p,
                                                      float* __restrict__ out) {
  int slot = blockIdx.x;
  if (slot >= *nsel_p) return;
  int tok = selt[slot];
  float wg = selw[slot];
  int t = threadIdx.x;
  const float4* y0 = (const float4*)(ypart + ((size_t)0*CAP + slot)*DMODEL);
  const float4* y1 = (const float4*)(ypart + ((size_t)1*CAP + slot)*DMODEL);
  const float4* y2 = (const float4*)(ypart + ((size_t)2*CAP + slot)*DMODEL);
  const float4* y3 = (const float4*)(ypart + ((size_t)3*CAP + slot)*DMODEL);
  float4 a = y0[t], b = y1[t], c = y2[t], d = y3[t];
  float4 s;
  s.x = a.x+b.x+c.x+d.x; s.y = a.y+b.y+c.y+d.y;
  s.z = a.z+b.z+c.z+d.z; s.w = a.w+b.w+c.w+d.w;
  float4* o = (float4*)(out + (size_t)tok*DMODEL);
  float4 ov = o[t];
  ov.x += wg*s.x; ov.y += wg*s.y; ov.z += wg*s.z; ov.w += wg*s.w;
  o[t] = ov;
}

// ---------------- launch ----------------
extern "C" void kernel_launch(void* const* d_in, const int* in_sizes, int n_in,
                              void* d_out, int out_size, void* d_ws, size_t ws_size,
                              hipStream_t stream) {
  const float* x  = (const float*)d_in[0];
  const float* Wg = (const float*)d_in[1];
  const float* W1 = (const float*)d_in[2];
  const float* W2 = (const float*)d_in[3];
  float* out = (float*)d_out;

  char* ws = (char*)d_ws;
  f16*   xf16  = (f16*)(ws + XF16_OFF);
  float* probs = (float*)(ws + PROBS_OFF);
  int*   tki   = (int*)(ws + TOPKI_OFF);
  float* tkv   = (float*)(ws + TOPKV_OFF);
  int*   listt = (int*)(ws + LISTT_OFF);
  float* listw = (float*)(ws + LISTW_OFF);
  int*   listf = (int*)(ws + LISTF_OFF);
  int*   selt  = (int*)(ws + SELT_OFF);
  float* selw  = (float*)(ws + SELW_OFF);
  float* imp   = (float*)(ws + IMP_OFF);
  int*   cnt   = (int*)(ws + CNT_OFF);
  int*   nsel  = (int*)(ws + NSEL_OFF);
  f16*   w1t   = (f16*)(ws + W1T_OFF);
  f16*   w2t   = (f16*)(ws + W2T_OFF);
  f16*   hbuf  = (f16*)(ws + H_OFF);
  float* ypart = (float*)(ws + YP_OFF);
  const char* zbuf = ws + ZERO_OFF;

  hipMemsetAsync(d_out, 0, (size_t)(S_TOK*DMODEL + 1)*sizeof(float), stream);
  hipMemsetAsync(ws, 0, 8192, stream);

  cvt_x_kernel<<<(S_TOK*DMODEL/8)/256, 256, 0, stream>>>(x, xf16);
  gate_kernel<<<S_TOK/4, 256, 0, stream>>>(x, Wg, probs, tki, tkv);
  imp_kernel<<<NEXP, 256, 0, stream>>>(probs, imp);
  compact_kernel<<<SK/256, 256, 0, stream>>>(tki, tkv, cnt, listt, listw, listf);
  select_kernel<<<NEXP, 1024, 0, stream>>>(listt, listw, listf, cnt, selt, selw, nsel);
  aux_kernel<<<1, 64, 0, stream>>>(imp, cnt, out + (size_t)S_TOK*DMODEL);

  for (int e = 0; e < NEXP; ++e) {
    const float* W1e = W1 + (size_t)e*DMODEL*HDIM;
    const float* W2e = W2 + (size_t)e*HDIM*DMODEL;
    tcvt_kernel<<<dim3(HDIM/32, DMODEL/32), dim3(32,8), 0, stream>>>(W1e, w1t, DMODEL, HDIM);
    tcvt_kernel<<<dim3(DMODEL/32, HDIM/32), dim3(32,8), 0, stream>>>(W2e, w2t, HDIM, DMODEL);
    gemm1_kernel<<<dim3(CAP/128, HDIM/128), 256, 0, stream>>>(xf16, w1t, selt + e*CAP, nsel + e, hbuf, zbuf);
    gemm2_kernel<<<dim3(CAP/128, DMODEL/128, NSPLIT), 256, 0, stream>>>(hbuf, w2t, nsel + e, ypart);
    combine_kernel<<<CAP, 256, 0, stream>>>(ypart, selt + e*CAP, selw + e*CAP, nsel + e, out);
  }
}

// Round 2
// 727.481 us; speedup vs baseline: 1.2768x; 1.2768x over previous
//
#include <hip/hip_runtime.h>
#include <hip/hip_fp16.h>
#include <math.h>

#define S_TOK 8192
#define DMODEL 1024
#define HDIM 4096
#define NEXP 8
#define KTOP2 2
#define CAP 2560
#define SK (S_TOK*KTOP2)
#define NSPLIT 4

typedef _Float16 f16;
typedef _Float16 f16x8 __attribute__((ext_vector_type(8)));
typedef float f32x4 __attribute__((ext_vector_type(4)));

typedef const __attribute__((address_space(1))) void* gas_cp;
typedef __attribute__((address_space(3))) void* las_p;

__device__ __forceinline__ void gload16(const void* g, void* l) {
  __builtin_amdgcn_global_load_lds((gas_cp)g, (las_p)l, 16, 0, 0);
}

// ---------------- ws layout (bytes) ----------------
static const size_t ZERO_OFF  = 0;          // 4096 zeroed every call
static const size_t IMP_OFF   = 4096;       // 8 floats
static const size_t CNT_OFF   = 4160;       // 8 ints
static const size_t NSEL_OFF  = 4224;       // 8 ints
static const size_t PROBS_OFF = 8192;
static const size_t TOPKI_OFF = 270336;
static const size_t TOPKV_OFF = 335872;
static const size_t LISTT_OFF = 401408;
static const size_t LISTW_OFF = 663552;
static const size_t LISTF_OFF = 925696;
static const size_t SELT_OFF  = 1187840;
static const size_t SELW_OFF  = 1269760;
static const size_t XF16_OFF  = 1351680;    // S*D f16 = 16MB
// ---- serial-fallback layout (proven <98MB) ----
static const size_t W1T_OFF   = 18128896;   // H*D f16 = 8MB
static const size_t W2T_OFF   = 26517504;   // D*H f16 = 8MB
static const size_t H_OFF     = 34906112;   // CAP*H f16 = 20MB
static const size_t YP_OFF    = 55877632;   // 4*CAP*D f32 = 40MB (end ~98MB)
// ---- fused layout (needs ~306MB) ----
static const size_t W1TA_OFF  = 18128896;                  // 8*H*D f16 = 64MB
static const size_t W2TA_OFF  = W1TA_OFF + (size_t)NEXP*HDIM*DMODEL*2;   // 64MB
static const size_t HA_OFF    = W2TA_OFF + (size_t)NEXP*DMODEL*HDIM*2;   // 8*CAP*H f16 = 160MB
static const size_t FUSED_NEED = HA_OFF + (size_t)NEXP*CAP*HDIM*2;       // ~305MB

// ---------------- x -> f16 ----------------
__global__ __launch_bounds__(256) void cvt_x_kernel(const float* __restrict__ x, f16* __restrict__ xf) {
  size_t i = (size_t)blockIdx.x*256 + threadIdx.x;
  const float4* xv = (const float4*)x;
  float4 a = xv[2*i], b = xv[2*i+1];
  union { f16 h[8]; uint4 u; } p;
  p.h[0]=(f16)a.x; p.h[1]=(f16)a.y; p.h[2]=(f16)a.z; p.h[3]=(f16)a.w;
  p.h[4]=(f16)b.x; p.h[5]=(f16)b.y; p.h[6]=(f16)b.z; p.h[7]=(f16)b.w;
  ((uint4*)xf)[i] = p.u;
}

// ---------------- gate: softmax + top2 ----------------
__global__ __launch_bounds__(256) void gate_kernel(const float* __restrict__ x, const float* __restrict__ Wg,
                                                   float* __restrict__ probs, int* __restrict__ tki,
                                                   float* __restrict__ tkv) {
  int lane = threadIdx.x & 63;
  int t = blockIdx.x*4 + (threadIdx.x >> 6);
  const float* xr = x + (size_t)t*DMODEL;
  float p[NEXP];
  #pragma unroll
  for (int e=0;e<NEXP;e++) p[e] = 0.f;
  for (int d = lane; d < DMODEL; d += 64) {
    float xv = xr[d];
    const float4* wg = (const float4*)(Wg + d*NEXP);
    float4 w0 = wg[0], w1 = wg[1];
    p[0] += xv*w0.x; p[1] += xv*w0.y; p[2] += xv*w0.z; p[3] += xv*w0.w;
    p[4] += xv*w1.x; p[5] += xv*w1.y; p[6] += xv*w1.z; p[7] += xv*w1.w;
  }
  #pragma unroll
  for (int off=32; off; off>>=1) {
    #pragma unroll
    for (int e=0;e<NEXP;e++) p[e] += __shfl_xor(p[e], off);
  }
  float mx = p[0];
  #pragma unroll
  for (int e=1;e<NEXP;e++) mx = fmaxf(mx, p[e]);
  float sum = 0.f;
  #pragma unroll
  for (int e=0;e<NEXP;e++) { p[e] = expf(p[e]-mx); sum += p[e]; }
  float inv = 1.f/sum;
  #pragma unroll
  for (int e=0;e<NEXP;e++) p[e] *= inv;
  if (lane == 0) {
    ((float4*)(probs + t*NEXP))[0] = make_float4(p[0],p[1],p[2],p[3]);
    ((float4*)(probs + t*NEXP))[1] = make_float4(p[4],p[5],p[6],p[7]);
    int i1 = 0; float v1 = p[0];
    #pragma unroll
    for (int e=1;e<NEXP;e++) if (p[e] > v1) { v1 = p[e]; i1 = e; }
    int i2 = -1; float v2 = -1.f;
    #pragma unroll
    for (int e=0;e<NEXP;e++) if (e != i1 && p[e] > v2) { v2 = p[e]; i2 = e; }
    tki[t*2] = i1; tki[t*2+1] = i2;
    tkv[t*2] = v1; tkv[t*2+1] = v2;
  }
}

// ---------------- importance ----------------
__global__ __launch_bounds__(256) void imp_kernel(const float* __restrict__ probs, float* __restrict__ imp) {
  int e = blockIdx.x;
  float s = 0.f;
  for (int t = threadIdx.x; t < S_TOK; t += 256) s += probs[t*NEXP + e];
  #pragma unroll
  for (int off=32; off; off>>=1) s += __shfl_xor(s, off);
  __shared__ float red[4];
  if ((threadIdx.x & 63) == 0) red[threadIdx.x>>6] = s;
  __syncthreads();
  if (threadIdx.x == 0) imp[e] = red[0]+red[1]+red[2]+red[3];
}

// ---------------- compact ----------------
__global__ __launch_bounds__(256) void compact_kernel(const int* __restrict__ tki, const float* __restrict__ tkv,
                                                      int* __restrict__ cnt, int* __restrict__ listt,
                                                      float* __restrict__ listw, int* __restrict__ listf) {
  int i = blockIdx.x*256 + threadIdx.x;
  int e = tki[i];
  int p = atomicAdd(&cnt[e], 1);
  listt[e*S_TOK + p] = i >> 1;
  listw[e*S_TOK + p] = tkv[i];
  listf[e*S_TOK + p] = i;
}

// ---------------- capacity selection ----------------
__global__ __launch_bounds__(1024) void select_kernel(const int* __restrict__ listt, const float* __restrict__ listw,
                                                      const int* __restrict__ listf, const int* __restrict__ cnt,
                                                      int* __restrict__ selt, float* __restrict__ selw,
                                                      int* __restrict__ nsel) {
  __shared__ float kw[8192];
  __shared__ unsigned short kf[8192];
  int e = blockIdx.x;
  int n = cnt[e];
  const int* lt = listt + e*S_TOK; const float* lw = listw + e*S_TOK; const int* lf = listf + e*S_TOK;
  int* st = selt + e*CAP; float* sw = selw + e*CAP;
  if (threadIdx.x == 0) nsel[e] = (n < CAP) ? n : CAP;
  if (n <= CAP) {
    for (int i = threadIdx.x; i < CAP; i += 1024) {
      if (i < n) { st[i] = lt[i]; sw[i] = lw[i]; }
      else       { st[i] = -1;    sw[i] = 0.f;  }
    }
  } else {
    for (int i = threadIdx.x; i < n; i += 1024) { kw[i] = lw[i]; kf[i] = (unsigned short)lf[i]; }
    __syncthreads();
    for (int i = threadIdx.x; i < n; i += 1024) {
      float wi = kw[i]; int fi = kf[i];
      int rank = 0;
      for (int j = 0; j < n; ++j) {
        float wj = kw[j];
        rank += (wj > wi) || (wj == wi && (int)kf[j] < fi);
      }
      if (rank < CAP) { st[rank] = lt[i]; sw[rank] = wi; }
    }
  }
}

// ---------------- aux loss ----------------
__global__ void aux_kernel(const float* __restrict__ imp, const int* __restrict__ cnt, float* __restrict__ aux_out) {
  if (threadIdx.x == 0 && blockIdx.x == 0) {
    float a = 0.f;
    #pragma unroll
    for (int e=0;e<NEXP;e++) a += imp[e] * (float)cnt[e];
    *aux_out = a * (8.0f / 67108864.0f);
  }
}

// ---------------- transpose + cvt (per-expert via blockIdx.z) ----------------
__global__ __launch_bounds__(256) void tcvt_kernel(const float* __restrict__ src0, f16* __restrict__ dst0,
                                                   int R, int C) {
  __shared__ float tile[32][33];
  const float* src = src0 + (size_t)blockIdx.z*R*C;
  f16* dst = dst0 + (size_t)blockIdx.z*R*C;
  int tx = threadIdx.x, ty = threadIdx.y;
  int c0 = blockIdx.x*32, r0 = blockIdx.y*32;
  #pragma unroll
  for (int j=0;j<4;j++)
    tile[ty + 8*j][tx] = src[(size_t)(r0 + ty + 8*j)*C + c0 + tx];
  __syncthreads();
  #pragma unroll
  for (int j=0;j<4;j++)
    dst[(size_t)(c0 + ty + 8*j)*R + r0 + tx] = (f16)tile[tx][ty + 8*j];
}

// ================= GEMM bodies =================
// 128x128 tile, BK=32, 4 waves x (64x64), double-buffered LDS via global_load_lds.

#define GEMM_PREAMBLE() \
  __shared__ __align__(16) f16 As[2][128*32]; \
  __shared__ __align__(16) f16 Bs[2][128*32]; \
  int tid = threadIdx.x; \
  int w = tid >> 6, l = tid & 63; \
  int rc0 = (w*2+0)*16 + (l>>2); \
  int rc1 = (w*2+1)*16 + (l>>2); \
  int scol = ((l&3)*16) ^ (((l>>2)&3) << 4); \
  int wr = w >> 1, wc = w & 1; \
  int fr = l & 15, kq = l >> 4; \
  int rsw = (fr & 3) << 4; \
  int aoff[4], boff[4]; \
  _Pragma("unroll") for (int m=0;m<4;m++) aoff[m] = (wr*64 + m*16 + fr)*64 + ((kq*16) ^ rsw); \
  _Pragma("unroll") for (int n=0;n<4;n++) boff[n] = (wc*64 + n*16 + fr)*64 + ((kq*16) ^ rsw); \
  f32x4 zero = {0.f,0.f,0.f,0.f}; \
  f32x4 acc[4][4]; \
  _Pragma("unroll") for (int m=0;m<4;m++) _Pragma("unroll") for (int n=0;n<4;n++) acc[m][n] = zero;

#define GEMM_STAGE(buf, kt) { int ko = (kt)*64; \
    gload16(sA0 + ko, &As[buf][(w*2+0)*512]); \
    gload16(sA1 + ko, &As[buf][(w*2+1)*512]); \
    gload16(sB0 + ko, &Bs[buf][(w*2+0)*512]); \
    gload16(sB1 + ko, &Bs[buf][(w*2+1)*512]); }

#define GEMM_MAINLOOP(KT) \
  GEMM_STAGE(0, 0); \
  __syncthreads(); \
  for (int kt = 0; kt < (KT); ++kt) { \
    int cur = kt & 1; \
    if (kt + 1 < (KT)) GEMM_STAGE(cur^1, kt+1); \
    const char* Ab = (const char*)As[cur]; \
    const char* Bb = (const char*)Bs[cur]; \
    f16x8 af[4], bf[4]; \
    _Pragma("unroll") for (int m=0;m<4;m++) af[m] = *(const f16x8*)(Ab + aoff[m]); \
    _Pragma("unroll") for (int n=0;n<4;n++) bf[n] = *(const f16x8*)(Bb + boff[n]); \
    _Pragma("unroll") for (int m=0;m<4;m++) \
      _Pragma("unroll") for (int n=0;n<4;n++) \
        acc[m][n] = __builtin_amdgcn_mfma_f32_16x16x32_f16(af[m], bf[n], acc[m][n], 0, 0, 0); \
    __syncthreads(); \
  }

// ---------------- GEMM1 fused over experts ----------------
__global__ __launch_bounds__(256) void gemm1_fused(const f16* __restrict__ xf, const f16* __restrict__ w1t_all,
                                                   const int* __restrict__ selt_all, const int* __restrict__ nsel_all,
                                                   f16* __restrict__ hbuf_all, const char* __restrict__ zbuf) {
  int bid = blockIdx.x;
  int wid = (bid & 7)*640 + (bid >> 3);      // XCD-chunked: each XCD = one expert
  int e = wid / 640; int rem = wid - e*640;  // 640 = 32 n-panels * 20 m-blocks
  int n0 = (rem / 20) * 128;
  int m0 = (rem % 20) * 128;
  int nsel = nsel_all[e];
  if (m0 >= nsel) return;
  const int* selt = selt_all + e*CAP;
  const f16* w1t = w1t_all + (size_t)e*HDIM*DMODEL;
  f16* hbuf = hbuf_all + (size_t)e*CAP*HDIM;

  GEMM_PREAMBLE();

  const char *sA0, *sA1;
  {
    int t0 = selt[m0 + rc0];
    int t1 = selt[m0 + rc1];
    sA0 = (t0 >= 0) ? ((const char*)(xf + (size_t)t0*DMODEL) + scol) : (zbuf + scol);
    sA1 = (t1 >= 0) ? ((const char*)(xf + (size_t)t1*DMODEL) + scol) : (zbuf + scol);
  }
  const char* sB0 = (const char*)(w1t + (size_t)(n0+rc0)*DMODEL) + scol;
  const char* sB1 = (const char*)(w1t + (size_t)(n0+rc1)*DMODEL) + scol;

  GEMM_MAINLOOP(DMODEL/32);

  int rowb = m0 + wr*64;
  int colb = n0 + wc*64;
  #pragma unroll
  for (int m=0;m<4;m++) {
    #pragma unroll
    for (int n=0;n<4;n++) {
      #pragma unroll
      for (int r=0;r<4;r++) {
        int row = rowb + m*16 + kq*4 + r;
        int col = colb + n*16 + fr;
        float v = acc[m][n][r];
        float g = 0.5f * v * (1.0f + erff(v * 0.70710678118654752f));
        hbuf[(size_t)row*HDIM + col] = (f16)g;
      }
    }
  }
}

// ---------------- GEMM2 fused: full K, weighted atomic scatter to out ----------------
__global__ __launch_bounds__(256) void gemm2_fused(const f16* __restrict__ hbuf_all, const f16* __restrict__ w2t_all,
                                                   const int* __restrict__ selt_all, const float* __restrict__ selw_all,
                                                   const int* __restrict__ nsel_all, float* __restrict__ out) {
  int bid = blockIdx.x;
  int wid = (bid & 7)*160 + (bid >> 3);      // 1280 blocks, XCD-chunked
  int e = wid / 160; int rem = wid - e*160;  // 160 = 8 n-panels * 20 m-blocks
  int n0 = (rem / 20) * 128;
  int m0 = (rem % 20) * 128;
  int nsel = nsel_all[e];
  if (m0 >= nsel) return;
  const f16* hb  = hbuf_all + (size_t)e*CAP*HDIM;
  const f16* w2t = w2t_all + (size_t)e*DMODEL*HDIM;

  GEMM_PREAMBLE();

  const char* sA0 = (const char*)(hb + (size_t)(m0+rc0)*HDIM) + scol;
  const char* sA1 = (const char*)(hb + (size_t)(m0+rc1)*HDIM) + scol;
  const char* sB0 = (const char*)(w2t + (size_t)(n0+rc0)*HDIM) + scol;
  const char* sB1 = (const char*)(w2t + (size_t)(n0+rc1)*HDIM) + scol;

  GEMM_MAINLOOP(HDIM/32);

  int rowb = m0 + wr*64;
  int colb = n0 + wc*64;
  #pragma unroll
  for (int m=0;m<4;m++) {
    #pragma unroll
    for (int r=0;r<4;r++) {
      int row = rowb + m*16 + kq*4 + r;
      int tok = selt_all[e*CAP + row];
      if (tok < 0) continue;
      float wg = selw_all[e*CAP + row];
      float* orow = out + (size_t)tok*DMODEL;
      #pragma unroll
      for (int n=0;n<4;n++) {
        int col = colb + n*16 + fr;
        atomicAdd(&orow[col], acc[m][n][r] * wg);
      }
    }
  }
}

// ================= serial-fallback kernels (round-1, proven) =================
__global__ __launch_bounds__(256) void gemm1_kernel(const f16* __restrict__ xf, const f16* __restrict__ w1t,
                                                    const int* __restrict__ selt, const int* __restrict__ nsel_p,
                                                    f16* __restrict__ hbuf, const char* __restrict__ zbuf) {
  int nsel = *nsel_p;
  int m0 = blockIdx.x * 128;
  if (m0 >= nsel) return;
  int n0 = blockIdx.y * 128;
  GEMM_PREAMBLE();
  const char *sA0, *sA1;
  {
    int t0 = selt[m0 + rc0];
    int t1 = selt[m0 + rc1];
    sA0 = (t0 >= 0) ? ((const char*)(xf + (size_t)t0*DMODEL) + scol) : (zbuf + scol);
    sA1 = (t1 >= 0) ? ((const char*)(xf + (size_t)t1*DMODEL) + scol) : (zbuf + scol);
  }
  const char* sB0 = (const char*)(w1t + (size_t)(n0+rc0)*DMODEL) + scol;
  const char* sB1 = (const char*)(w1t + (size_t)(n0+rc1)*DMODEL) + scol;
  GEMM_MAINLOOP(DMODEL/32);
  int rowb = m0 + wr*64;
  int colb = n0 + wc*64;
  #pragma unroll
  for (int m=0;m<4;m++)
    #pragma unroll
    for (int n=0;n<4;n++)
      #pragma unroll
      for (int r=0;r<4;r++) {
        int row = rowb + m*16 + kq*4 + r;
        int col = colb + n*16 + fr;
        float v = acc[m][n][r];
        float g = 0.5f * v * (1.0f + erff(v * 0.70710678118654752f));
        hbuf[(size_t)row*HDIM + col] = (f16)g;
      }
}

__global__ __launch_bounds__(256) void gemm2_kernel(const f16* __restrict__ hbuf, const f16* __restrict__ w2t,
                                                    const int* __restrict__ nsel_p, float* __restrict__ ypart) {
  int nsel = *nsel_p;
  int m0 = blockIdx.x * 128;
  if (m0 >= nsel) return;
  int n0 = blockIdx.y * 128;
  int z  = blockIdx.z;
  GEMM_PREAMBLE();
  const char* sA0 = (const char*)(hbuf + (size_t)(m0+rc0)*HDIM) + z*2048 + scol;
  const char* sA1 = (const char*)(hbuf + (size_t)(m0+rc1)*HDIM) + z*2048 + scol;
  const char* sB0 = (const char*)(w2t + (size_t)(n0+rc0)*HDIM) + z*2048 + scol;
  const char* sB1 = (const char*)(w2t + (size_t)(n0+rc1)*HDIM) + z*2048 + scol;
  GEMM_MAINLOOP(1024/32);
  int rowb = m0 + wr*64;
  int colb = n0 + wc*64;
  #pragma unroll
  for (int m=0;m<4;m++)
    #pragma unroll
    for (int n=0;n<4;n++)
      #pragma unroll
      for (int r=0;r<4;r++) {
        int row = rowb + m*16 + kq*4 + r;
        int col = colb + n*16 + fr;
        ypart[((size_t)z*CAP + row)*DMODEL + col] = acc[m][n][r];
      }
}

__global__ __launch_bounds__(256) void combine_kernel(const float* __restrict__ ypart, const int* __restrict__ selt,
                                                      const float* __restrict__ selw, const int* __restrict__ nsel_p,
                                                      float* __restrict__ out) {
  int slot = blockIdx.x;
  if (slot >= *nsel_p) return;
  int tok = selt[slot];
  float wg = selw[slot];
  int t = threadIdx.x;
  const float4* y0 = (const float4*)(ypart + ((size_t)0*CAP + slot)*DMODEL);
  const float4* y1 = (const float4*)(ypart + ((size_t)1*CAP + slot)*DMODEL);
  const float4* y2 = (const float4*)(ypart + ((size_t)2*CAP + slot)*DMODEL);
  const float4* y3 = (const float4*)(ypart + ((size_t)3*CAP + slot)*DMODEL);
  float4 a = y0[t], b = y1[t], c = y2[t], d = y3[t];
  float4 s;
  s.x = a.x+b.x+c.x+d.x; s.y = a.y+b.y+c.y+d.y;
  s.z = a.z+b.z+c.z+d.z; s.w = a.w+b.w+c.w+d.w;
  float4* o = (float4*)(out + (size_t)tok*DMODEL);
  float4 ov = o[t];
  ov.x += wg*s.x; ov.y += wg*s.y; ov.z += wg*s.z; ov.w += wg*s.w;
  o[t] = ov;
}

// ---------------- launch ----------------
extern "C" void kernel_launch(void* const* d_in, const int* in_sizes, int n_in,
                              void* d_out, int out_size, void* d_ws, size_t ws_size,
                              hipStream_t stream) {
  const float* x  = (const float*)d_in[0];
  const float* Wg = (const float*)d_in[1];
  const float* W1 = (const float*)d_in[2];
  const float* W2 = (const float*)d_in[3];
  float* out = (float*)d_out;

  char* ws = (char*)d_ws;
  f16*   xf16  = (f16*)(ws + XF16_OFF);
  float* probs = (float*)(ws + PROBS_OFF);
  int*   tki   = (int*)(ws + TOPKI_OFF);
  float* tkv   = (float*)(ws + TOPKV_OFF);
  int*   listt = (int*)(ws + LISTT_OFF);
  float* listw = (float*)(ws + LISTW_OFF);
  int*   listf = (int*)(ws + LISTF_OFF);
  int*   selt  = (int*)(ws + SELT_OFF);
  float* selw  = (float*)(ws + SELW_OFF);
  float* imp   = (float*)(ws + IMP_OFF);
  int*   cnt   = (int*)(ws + CNT_OFF);
  int*   nsel  = (int*)(ws + NSEL_OFF);
  const char* zbuf = ws + ZERO_OFF;

  hipMemsetAsync(d_out, 0, (size_t)(S_TOK*DMODEL + 1)*sizeof(float), stream);
  hipMemsetAsync(ws, 0, 8192, stream);

  cvt_x_kernel<<<(S_TOK*DMODEL/8)/256, 256, 0, stream>>>(x, xf16);
  gate_kernel<<<S_TOK/4, 256, 0, stream>>>(x, Wg, probs, tki, tkv);
  imp_kernel<<<NEXP, 256, 0, stream>>>(probs, imp);
  compact_kernel<<<SK/256, 256, 0, stream>>>(tki, tkv, cnt, listt, listw, listf);
  select_kernel<<<NEXP, 1024, 0, stream>>>(listt, listw, listf, cnt, selt, selw, nsel);
  aux_kernel<<<1, 64, 0, stream>>>(imp, cnt, out + (size_t)S_TOK*DMODEL);

  if (ws_size >= FUSED_NEED) {
    f16* w1t_all = (f16*)(ws + W1TA_OFF);
    f16* w2t_all = (f16*)(ws + W2TA_OFF);
    f16* hbuf_all = (f16*)(ws + HA_OFF);
    // transpose+cvt all experts
    tcvt_kernel<<<dim3(HDIM/32, DMODEL/32, NEXP), dim3(32,8), 0, stream>>>(W1, w1t_all, DMODEL, HDIM);
    tcvt_kernel<<<dim3(DMODEL/32, HDIM/32, NEXP), dim3(32,8), 0, stream>>>(W2, w2t_all, HDIM, DMODEL);
    gemm1_fused<<<NEXP*640, 256, 0, stream>>>(xf16, w1t_all, selt, nsel, hbuf_all, zbuf);
    gemm2_fused<<<NEXP*160, 256, 0, stream>>>(hbuf_all, w2t_all, selt, selw, nsel, out);
  } else {
    f16* w1t = (f16*)(ws + W1T_OFF);
    f16* w2t = (f16*)(ws + W2T_OFF);
    f16* hbuf = (f16*)(ws + H_OFF);
    float* ypart = (float*)(ws + YP_OFF);
    for (int e = 0; e < NEXP; ++e) {
      const float* W1e = W1 + (size_t)e*DMODEL*HDIM;
      const float* W2e = W2 + (size_t)e*HDIM*DMODEL;
      tcvt_kernel<<<dim3(HDIM/32, DMODEL/32, 1), dim3(32,8), 0, stream>>>(W1e, w1t, DMODEL, HDIM);
      tcvt_kernel<<<dim3(DMODEL/32, HDIM/32, 1), dim3(32,8), 0, stream>>>(W2e, w2t, HDIM, DMODEL);
      gemm1_kernel<<<dim3(CAP/128, HDIM/128), 256, 0, stream>>>(xf16, w1t, selt + e*CAP, nsel + e, hbuf, zbuf);
      gemm2_kernel<<<dim3(CAP/128, DMODEL/128, NSPLIT), 256, 0, stream>>>(hbuf, w2t, nsel + e, ypart);
      combine_kernel<<<CAP, 256, 0, stream>>>(ypart, selt + e*CAP, selw + e*CAP, nsel + e, out);
    }
  }
}